// Round 7
// baseline (494.300 us; speedup 1.0000x reference)
//
#include <hip/hip_runtime.h>
#include <hip/hip_bf16.h>

// Problem constants (match reference)
constexpr int N_NODES = 50000;
constexpr int N_EDGES = 600000;
constexpr int D       = 128;   // IN_DIM == FEAT
constexpr int N_CLS   = 40;

using bf16x8 = __attribute__((ext_vector_type(8))) short;   // 8 bf16 = 4 VGPR
using f32x4  = __attribute__((ext_vector_type(4))) float;   // MFMA C/D

__device__ inline unsigned short f2bf(float f) {
    __hip_bfloat16 h = __float2bfloat16(f);
    return __builtin_bit_cast(unsigned short, h);
}
__device__ inline float bf2f(unsigned short u) {
    __hip_bfloat16 h = __builtin_bit_cast(__hip_bfloat16, u);
    return __bfloat162float(h);
}

// ---------------------------------------------------------------------------
// CSR build: histogram -> block scan -> sum scan -> finalize -> scatter
// ---------------------------------------------------------------------------

__global__ void hist_kernel(const int* __restrict__ ei, int* __restrict__ cnt) {
    int e = blockIdx.x * 256 + threadIdx.x;
    if (e < N_EDGES) atomicAdd(&cnt[ei[N_EDGES + e]], 1);
}

__global__ __launch_bounds__(1024) void scan_block_kernel(const int* __restrict__ cnt,
                                                          int* __restrict__ rs,
                                                          int* __restrict__ bsum, int n) {
    __shared__ int t[1024];
    int tid = threadIdx.x;
    int gid = blockIdx.x * 1024 + tid;
    int v = (gid < n) ? cnt[gid] : 0;
    t[tid] = v;
    __syncthreads();
    for (int off = 1; off < 1024; off <<= 1) {
        int u = (tid >= off) ? t[tid - off] : 0;
        __syncthreads();
        t[tid] += u;
        __syncthreads();
    }
    if (gid < n) rs[gid] = t[tid] - v;          // exclusive within block
    if (tid == 1023) bsum[blockIdx.x] = t[1023];
}

__global__ void scan_sums_kernel(const int* __restrict__ bsum, int* __restrict__ boff, int nblk) {
    __shared__ int t[64];
    int tid = threadIdx.x;
    int v = (tid < nblk) ? bsum[tid] : 0;
    t[tid] = v;
    __syncthreads();
    for (int off = 1; off < 64; off <<= 1) {
        int u = (tid >= off) ? t[tid - off] : 0;
        __syncthreads();
        t[tid] += u;
        __syncthreads();
    }
    if (tid < nblk) boff[tid] = t[tid] - v;     // exclusive
}

__global__ void finalize_kernel(const int* __restrict__ cnt, int* __restrict__ rs,
                                int* __restrict__ cursor, float* __restrict__ dinv,
                                const int* __restrict__ boff) {
    int i = blockIdx.x * 256 + threadIdx.x;
    if (i < N_NODES) {
        int v = rs[i] + boff[i >> 10];
        rs[i] = v;
        cursor[i] = v;
        dinv[i] = 1.0f / fmaxf((float)cnt[i], 1.0f);
        if (i == 0) rs[N_NODES] = N_EDGES;
    }
}

__global__ void scatter_kernel(const int* __restrict__ ei, int* __restrict__ cursor,
                               int* __restrict__ csr) {
    int e = blockIdx.x * 256 + threadIdx.x;
    if (e < N_EDGES) {
        int d = ei[N_EDGES + e];
        int p = atomicAdd(&cursor[d], 1);
        csr[p] = ei[e];
    }
}

// ---------------------------------------------------------------------------
// Weight split, all 3 layers: w123h/l[layer][n][256] = split [Wl | Wr]
// ---------------------------------------------------------------------------
__global__ void split_w3_kernel(const float* __restrict__ Wl1, const float* __restrict__ Wr1,
                                const float* __restrict__ Wl2, const float* __restrict__ Wr2,
                                const float* __restrict__ Wl3, const float* __restrict__ Wr3,
                                unsigned short* __restrict__ hi, unsigned short* __restrict__ lo) {
    int layer = blockIdx.x >> 7;                       // 0..2
    int idx = (blockIdx.x & 127) * 256 + threadIdx.x;  // 0..32767
    int n = idx >> 8, k = idx & 255;
    const float* Wl = (layer == 0) ? Wl1 : (layer == 1) ? Wl2 : Wl3;
    const float* Wr = (layer == 0) ? Wr1 : (layer == 1) ? Wr2 : Wr3;
    float v = (k < 128) ? Wl[n * 128 + k] : Wr[n * 128 + (k - 128)];
    unsigned short h = f2bf(v);
    size_t o = (size_t)layer * 32768 + idx;
    hi[o] = h;
    lo[o] = f2bf(v - bf2f(h));
}

// Classifier weight split: wc_h/l[48][128] (rows 40..47 zero-padded)
__global__ void split_wc_kernel(const float* __restrict__ Wc,
                                unsigned short* __restrict__ hi, unsigned short* __restrict__ lo) {
    int idx = blockIdx.x * 256 + threadIdx.x;   // 0..6143
    int n = idx >> 7, k = idx & 127;
    float v = (n < N_CLS) ? Wc[n * 128 + k] : 0.f;
    unsigned short h = f2bf(v);
    hi[idx] = h;
    lo[idx] = f2bf(v - bf2f(h));
}

// ===========================================================================
// FUSED SAGE layer: per 64-node block:
//   phase G: gather-mean in-edges of the block's nodes (wave=16 nodes,
//            lane=float2 of a 512B row, 8 edges in flight), *deg_inv,
//            split fp32->bf16 hi/lo straight into LDS A-tiles (k 0..127).
//   phase M: 4 k-tiles of split-bf16 MFMA vs Wcat^T ([Wl|Wr], K=256);
//            kt>=2 stages Ax (=feat rows) over the consumed agg tiles.
//   epilogue: relu(acc+bias) -> outp  (CLS variant: + resid, fused classifier)
// LDS 64KB: A 2 tiles hi (16K) + 2 lo (16K) + W hi (16K) + W lo (16K)
// ===========================================================================

#define GATHER_PHASE                                                             \
    for (int i = 0; i < 16; ++i) {                                               \
        int rloc = wid * 16 + i;                                                 \
        int gn = row0 + rloc;                                                    \
        if (gn >= M) gn = M - 1;                                                 \
        int e0 = rs[gn], e1 = rs[gn + 1];                                        \
        float ax = 0.f, ay = 0.f;                                                \
        for (int b = e0; b < e1; b += 64) {                                      \
            int cnt = min(64, e1 - b);                                           \
            int idxv = (lane < cnt) ? csr[b + lane] : 0;                         \
            int j = 0;                                                           \
            for (; j + 8 <= cnt; j += 8) {                                       \
                int s0 = __shfl(idxv, j + 0), s1 = __shfl(idxv, j + 1);          \
                int s2 = __shfl(idxv, j + 2), s3 = __shfl(idxv, j + 3);          \
                int s4 = __shfl(idxv, j + 4), s5 = __shfl(idxv, j + 5);          \
                int s6 = __shfl(idxv, j + 6), s7 = __shfl(idxv, j + 7);          \
                float2 v0 = *(const float2*)&feat[(size_t)s0 * D + lane * 2];    \
                float2 v1 = *(const float2*)&feat[(size_t)s1 * D + lane * 2];    \
                float2 v2 = *(const float2*)&feat[(size_t)s2 * D + lane * 2];    \
                float2 v3 = *(const float2*)&feat[(size_t)s3 * D + lane * 2];    \
                float2 v4 = *(const float2*)&feat[(size_t)s4 * D + lane * 2];    \
                float2 v5 = *(const float2*)&feat[(size_t)s5 * D + lane * 2];    \
                float2 v6 = *(const float2*)&feat[(size_t)s6 * D + lane * 2];    \
                float2 v7 = *(const float2*)&feat[(size_t)s7 * D + lane * 2];    \
                ax += v0.x + v1.x + v2.x + v3.x + v4.x + v5.x + v6.x + v7.x;     \
                ay += v0.y + v1.y + v2.y + v3.y + v4.y + v5.y + v6.y + v7.y;     \
            }                                                                    \
            for (; j < cnt; ++j) {                                               \
                int s = __shfl(idxv, j);                                         \
                float2 v = *(const float2*)&feat[(size_t)s * D + lane * 2];      \
                ax += v.x; ay += v.y;                                            \
            }                                                                    \
        }                                                                        \
        float di = dinv[gn];                                                     \
        ax *= di; ay *= di;                                                      \
        unsigned short h0 = f2bf(ax), l0 = f2bf(ax - bf2f(h0));                  \
        unsigned short h1 = f2bf(ay), l1 = f2bf(ay - bf2f(h1));                  \
        int t = lane >> 5;                                                       \
        int kloc = (lane * 2) & 63;                                              \
        int boff = (rloc << 7) + (kloc << 1);                                    \
        boff ^= (rloc & 7) << 4;                                                 \
        *(unsigned int*)(AhT + t * 8192 + boff) = (unsigned)h0 | ((unsigned)h1 << 16); \
        *(unsigned int*)(AlT + t * 8192 + boff) = (unsigned)l0 | ((unsigned)l1 << 16); \
    }                                                                            \
    __syncthreads();

#define KT_LOOP                                                                  \
    for (int kt = 0; kt < 4; ++kt) {                                             \
        int tb = (kt < 2 ? kt : kt - 2) * 8192;                                  \
        if (kt >= 2) {                                                           \
            int kcol = (kt & 1) * 64;                                            \
            _Pragma("unroll")                                                    \
            for (int it = 0; it < 2; ++it) {                                     \
                int slot = tid + it * 256;                                       \
                int row = slot >> 3;                                             \
                int k8 = (slot & 7) * 8;                                         \
                int gr = row0 + row;                                             \
                if (gr >= M) gr = M - 1;                                         \
                const float* p = &feat[(size_t)gr * D + kcol + k8];              \
                float4 v0 = *(const float4*)p;                                   \
                float4 v1 = *(const float4*)(p + 4);                             \
                float fv[8] = {v0.x, v0.y, v0.z, v0.w, v1.x, v1.y, v1.z, v1.w};  \
                union { unsigned short u[8]; uint4 q; } ph, pl;                  \
                _Pragma("unroll")                                                \
                for (int j = 0; j < 8; ++j) {                                    \
                    unsigned short h = f2bf(fv[j]);                              \
                    ph.u[j] = h;                                                 \
                    pl.u[j] = f2bf(fv[j] - bf2f(h));                             \
                }                                                                \
                int boff = (row << 7) + (k8 << 1);                               \
                boff ^= (row & 7) << 4;                                          \
                *(uint4*)(AhT + tb + boff) = ph.q;                               \
                *(uint4*)(AlT + tb + boff) = pl.q;                               \
            }                                                                    \
        }                                                                        \
        _Pragma("unroll")                                                        \
        for (int it = 0; it < 4; ++it) {                                         \
            int slot = tid + it * 256;                                           \
            int n = slot >> 3;                                                   \
            int k8 = (slot & 7) * 8;                                             \
            size_t gsrc = (size_t)n * 256 + kt * 64 + k8;                        \
            uint4 h = *(const uint4*)&Whi[gsrc];                                 \
            uint4 l = *(const uint4*)&Wlo[gsrc];                                 \
            int boff = (n << 7) + (k8 << 1);                                     \
            boff ^= (n & 7) << 4;                                                \
            *(uint4*)(WhB + boff) = h;                                           \
            *(uint4*)(WlB + boff) = l;                                           \
        }                                                                        \
        __syncthreads();                                                         \
        _Pragma("unroll")                                                        \
        for (int ks = 0; ks < 2; ++ks) {                                         \
            int kk = ks * 32 + kg;                                               \
            bf16x8 ah[2], al[2];                                                 \
            _Pragma("unroll")                                                    \
            for (int f = 0; f < 2; ++f) {                                        \
                int row = wr * 32 + f * 16 + lr;                                 \
                int boff = (row << 7) + (kk << 1);                               \
                boff ^= (row & 7) << 4;                                          \
                ah[f] = *(const bf16x8*)(AhT + tb + boff);                       \
                al[f] = *(const bf16x8*)(AlT + tb + boff);                       \
            }                                                                    \
            bf16x8 bh[4], bl[4];                                                 \
            _Pragma("unroll")                                                    \
            for (int j = 0; j < 4; ++j) {                                        \
                int n = wc * 64 + j * 16 + lr;                                   \
                int boff = (n << 7) + (kk << 1);                                 \
                boff ^= (n & 7) << 4;                                            \
                bh[j] = *(const bf16x8*)(WhB + boff);                            \
                bl[j] = *(const bf16x8*)(WlB + boff);                            \
            }                                                                    \
            _Pragma("unroll")                                                    \
            for (int f = 0; f < 2; ++f)                                          \
                _Pragma("unroll")                                                \
                for (int j = 0; j < 4; ++j) {                                    \
                    acc[f][j] = __builtin_amdgcn_mfma_f32_16x16x32_bf16(ah[f], bh[j], acc[f][j], 0, 0, 0); \
                    acc[f][j] = __builtin_amdgcn_mfma_f32_16x16x32_bf16(ah[f], bl[j], acc[f][j], 0, 0, 0); \
                    acc[f][j] = __builtin_amdgcn_mfma_f32_16x16x32_bf16(al[f], bh[j], acc[f][j], 0, 0, 0); \
                }                                                                \
        }                                                                        \
        __syncthreads();                                                         \
    }

__global__ __launch_bounds__(256) void fused_sage_kernel(const float* __restrict__ feat,
                                                         const int* __restrict__ rs,
                                                         const int* __restrict__ csr,
                                                         const float* __restrict__ dinv,
                                                         const unsigned short* __restrict__ Whi,
                                                         const unsigned short* __restrict__ Wlo,
                                                         const float* __restrict__ bias,
                                                         float* __restrict__ outp, int M) {
    __shared__ __align__(16) char smem[65536];
    char* AhT = smem;                 // 2 tiles x 8KB
    char* AlT = smem + 16384;
    char* WhB = smem + 32768;
    char* WlB = smem + 49152;

    int tid = threadIdx.x;
    int lane = tid & 63;
    int wid = tid >> 6;
    int wr = wid >> 1;
    int wc = wid & 1;
    int lr = lane & 15;
    int kg = (lane >> 4) * 8;
    int row0 = blockIdx.x * 64;

    f32x4 acc[2][4];
#pragma unroll
    for (int f = 0; f < 2; ++f)
#pragma unroll
        for (int j = 0; j < 4; ++j) acc[f][j] = (f32x4){0.f, 0.f, 0.f, 0.f};

    GATHER_PHASE
    KT_LOOP

    // epilogue: bias + relu. D map: row=(l>>4)*4+r, col=l&15
#pragma unroll
    for (int f = 0; f < 2; ++f)
#pragma unroll
        for (int j = 0; j < 4; ++j) {
            int c = wc * 64 + j * 16 + lr;
            float b = bias[c];
#pragma unroll
            for (int r = 0; r < 4; ++r) {
                int gr = row0 + wr * 32 + f * 16 + (lane >> 4) * 4 + r;
                if (gr < M) outp[(size_t)gr * D + c] = fmaxf(acc[f][j][r] + b, 0.f);
            }
        }
}

__global__ __launch_bounds__(256) void fused_cls_kernel(const float* __restrict__ feat,
                                                        const int* __restrict__ rs,
                                                        const int* __restrict__ csr,
                                                        const float* __restrict__ dinv,
                                                        const unsigned short* __restrict__ Whi,
                                                        const unsigned short* __restrict__ Wlo,
                                                        const float* __restrict__ bias,
                                                        const float* __restrict__ residf,
                                                        const unsigned short* __restrict__ Wch,
                                                        const unsigned short* __restrict__ Wcl,
                                                        const float* __restrict__ bc,
                                                        float* __restrict__ outp, int M) {
    __shared__ __align__(16) char smem[65536];
    char* AhT = smem;
    char* AlT = smem + 16384;
    char* WhB = smem + 32768;
    char* WlB = smem + 49152;

    int tid = threadIdx.x;
    int lane = tid & 63;
    int wid = tid >> 6;
    int wr = wid >> 1;
    int wc = wid & 1;
    int lr = lane & 15;
    int kg = (lane >> 4) * 8;
    int row0 = blockIdx.x * 64;

    f32x4 acc[2][4];
#pragma unroll
    for (int f = 0; f < 2; ++f)
#pragma unroll
        for (int j = 0; j < 4; ++j) acc[f][j] = (f32x4){0.f, 0.f, 0.f, 0.f};

    GATHER_PHASE
    KT_LOOP

    // classifier: 2 phases over vif col-halves (vif kept in LDS tile0)
    f32x4 acc2[3];
#pragma unroll
    for (int j = 0; j < 3; ++j) acc2[j] = (f32x4){0.f, 0.f, 0.f, 0.f};

    for (int p = 0; p < 2; ++p) {
        // stage Wc half: 48 x 64 bf16 hi/lo
#pragma unroll
        for (int it = 0; it < 2; ++it) {
            int slot = tid + it * 256;
            if (slot < 384) {
                int n = slot >> 3;
                int k8 = (slot & 7) * 8;
                size_t gsrc = (size_t)n * 128 + p * 64 + k8;
                uint4 h = *(const uint4*)&Wch[gsrc];
                uint4 l = *(const uint4*)&Wcl[gsrc];
                int boff = (n << 7) + (k8 << 1);
                boff ^= (n & 7) << 4;
                *(uint4*)(WhB + boff) = h;
                *(uint4*)(WlB + boff) = l;
            }
        }
        // waves owning col-half p write vif = relu(acc+bias)+resid (bf16 hi/lo)
        if (wc == p) {
#pragma unroll
            for (int f = 0; f < 2; ++f)
#pragma unroll
                for (int j = 0; j < 4; ++j) {
                    int c = wc * 64 + j * 16 + lr;
                    float b = bias[c];
#pragma unroll
                    for (int r = 0; r < 4; ++r) {
                        int row = wr * 32 + f * 16 + (lane >> 4) * 4 + r;
                        int gr = row0 + row;
                        int gra = (gr < M) ? gr : (M - 1);
                        float v = fmaxf(acc[f][j][r] + b, 0.f);
                        v += residf[(size_t)gra * D + c];
                        int kloc = j * 16 + lr;
                        int boff = (row << 7) + (kloc << 1);
                        boff ^= (row & 7) << 4;
                        unsigned short h = f2bf(v);
                        *(unsigned short*)(AhT + boff) = h;
                        *(unsigned short*)(AlT + boff) = f2bf(v - bf2f(h));
                    }
                }
        }
        __syncthreads();

        // each wave: 16 rows x 48 cols over this 64-k half
#pragma unroll
        for (int ks = 0; ks < 2; ++ks) {
            int kk = ks * 32 + kg;
            int row = wid * 16 + lr;
            int boffA = (row << 7) + (kk << 1);
            boffA ^= (row & 7) << 4;
            bf16x8 ah = *(const bf16x8*)(AhT + boffA);
            bf16x8 al = *(const bf16x8*)(AlT + boffA);
#pragma unroll
            for (int j = 0; j < 3; ++j) {
                int n = j * 16 + lr;
                int boffB = (n << 7) + (kk << 1);
                boffB ^= (n & 7) << 4;
                bf16x8 bh = *(const bf16x8*)(WhB + boffB);
                bf16x8 bl = *(const bf16x8*)(WlB + boffB);
                acc2[j] = __builtin_amdgcn_mfma_f32_16x16x32_bf16(ah, bh, acc2[j], 0, 0, 0);
                acc2[j] = __builtin_amdgcn_mfma_f32_16x16x32_bf16(ah, bl, acc2[j], 0, 0, 0);
                acc2[j] = __builtin_amdgcn_mfma_f32_16x16x32_bf16(al, bh, acc2[j], 0, 0, 0);
            }
        }
        __syncthreads();
    }

    // store out[M,40]
#pragma unroll
    for (int j = 0; j < 3; ++j) {
        int c = j * 16 + lr;
        if (c < N_CLS) {
            float b = bc[c];
#pragma unroll
            for (int r = 0; r < 4; ++r) {
                int gr = row0 + wid * 16 + (lane >> 4) * 4 + r;
                if (gr < M) outp[(size_t)gr * N_CLS + c] = acc2[j][r] + b;
            }
        }
    }
}

// ---------------------------------------------------------------------------
extern "C" void kernel_launch(void* const* d_in, const int* in_sizes, int n_in,
                              void* d_out, int out_size, void* d_ws, size_t ws_size,
                              hipStream_t stream) {
    const float* x   = (const float*)d_in[0];
    const int*   ei  = (const int*)d_in[1];
    const float* Wl1 = (const float*)d_in[2];
    const float* bl1 = (const float*)d_in[3];
    const float* Wr1 = (const float*)d_in[4];
    const float* Wl2 = (const float*)d_in[5];
    const float* bl2 = (const float*)d_in[6];
    const float* Wr2 = (const float*)d_in[7];
    const float* Wl3 = (const float*)d_in[8];
    const float* bl3 = (const float*)d_in[9];
    const float* Wr3 = (const float*)d_in[10];
    const float* Wc  = (const float*)d_in[11];
    const float* bc  = (const float*)d_in[12];
    float* out = (float*)d_out;

    char* w = (char*)d_ws;
    size_t off = 0;
    auto carve = [&](size_t bytes) -> void* {
        void* p = w + off;
        off = (off + bytes + 255) & ~(size_t)255;
        return p;
    };
    int*   cnt    = (int*)carve((size_t)N_NODES * 4);
    int*   rs     = (int*)carve((size_t)(N_NODES + 1) * 4);
    int*   cursor = (int*)carve((size_t)N_NODES * 4);
    float* dinv   = (float*)carve((size_t)N_NODES * 4);
    int*   bsum   = (int*)carve(64 * 4);
    int*   boff   = (int*)carve(64 * 4);
    int*   csr    = (int*)carve((size_t)N_EDGES * 4);
    float* bufA   = (float*)carve((size_t)N_NODES * D * 4);   // 25.6 MB
    float* bufB   = (float*)carve((size_t)N_NODES * D * 4);   // 25.6 MB
    unsigned short* w123h = (unsigned short*)carve(3 * 128 * 256 * 2);
    unsigned short* w123l = (unsigned short*)carve(3 * 128 * 256 * 2);
    unsigned short* wch   = (unsigned short*)carve(48 * 128 * 2);
    unsigned short* wcl   = (unsigned short*)carve(48 * 128 * 2);
    (void)ws_size;

    const int NBLK_SCAN = (N_NODES + 1023) / 1024;           // 49
    const int GRID_E = (N_EDGES + 255) / 256;                // 2344
    const int GRID_N = (N_NODES + 255) / 256;                // 196
    const int GRID_GEMM = (N_NODES + 63) / 64;               // 782

    // CSR build + weight splits
    hipMemsetAsync(cnt, 0, (size_t)N_NODES * 4, stream);
    hipLaunchKernelGGL(hist_kernel, dim3(GRID_E), dim3(256), 0, stream, ei, cnt);
    hipLaunchKernelGGL(split_w3_kernel, dim3(384), dim3(256), 0, stream,
                       Wl1, Wr1, Wl2, Wr2, Wl3, Wr3, w123h, w123l);
    hipLaunchKernelGGL(split_wc_kernel, dim3(24), dim3(256), 0, stream, Wc, wch, wcl);
    hipLaunchKernelGGL(scan_block_kernel, dim3(NBLK_SCAN), dim3(1024), 0, stream, cnt, rs, bsum, N_NODES);
    hipLaunchKernelGGL(scan_sums_kernel, dim3(1), dim3(64), 0, stream, bsum, boff, NBLK_SCAN);
    hipLaunchKernelGGL(finalize_kernel, dim3(GRID_N), dim3(256), 0, stream, cnt, rs, cursor, dinv, boff);
    hipLaunchKernelGGL(scatter_kernel, dim3(GRID_E), dim3(256), 0, stream, ei, cursor, csr);

    // Layer 1 (gather from x, Ax = x)
    hipLaunchKernelGGL(fused_sage_kernel, dim3(GRID_GEMM), dim3(256), 0, stream,
                       x, rs, csr, dinv, w123h, w123l, bl1, bufA, N_NODES);
    // Layer 2
    hipLaunchKernelGGL(fused_sage_kernel, dim3(GRID_GEMM), dim3(256), 0, stream,
                       bufA, rs, csr, dinv, w123h + 32768, w123l + 32768, bl2, bufB, N_NODES);
    // Layer 3 + residual + classifier
    hipLaunchKernelGGL(fused_cls_kernel, dim3(GRID_GEMM), dim3(256), 0, stream,
                       bufB, rs, csr, dinv, w123h + 65536, w123l + 65536, bl3, bufB,
                       wch, wcl, bc, out, N_NODES);
}

// Round 8
// 341.427 us; speedup vs baseline: 1.4477x; 1.4477x over previous
//
#include <hip/hip_runtime.h>
#include <hip/hip_bf16.h>

// Problem constants (match reference)
constexpr int N_NODES = 50000;
constexpr int N_EDGES = 600000;
constexpr int D       = 128;   // IN_DIM == FEAT
constexpr int N_CLS   = 40;

constexpr float QS = 2048.0f;          // layer-3 gather-table quant scale
constexpr float DQ = 1.0f / 2048.0f;

using bf16x8 = __attribute__((ext_vector_type(8))) short;   // 8 bf16 = 4 VGPR
using f32x4  = __attribute__((ext_vector_type(4))) float;   // MFMA C/D

__device__ inline unsigned short f2bf(float f) {
    __hip_bfloat16 h = __float2bfloat16(f);
    return __builtin_bit_cast(unsigned short, h);
}
__device__ inline float bf2f(unsigned short u) {
    __hip_bfloat16 h = __builtin_bit_cast(__hip_bfloat16, u);
    return __bfloat162float(h);
}
__device__ inline short q16(float v) {
    float s = v * QS;
    s = fminf(fmaxf(s, -32767.f), 32767.f);
    return (short)__float2int_rn(s);
}

// ---------------------------------------------------------------------------
// CSR build: histogram -> block scan -> finalize(+sum-scan) -> scatter
// ---------------------------------------------------------------------------

__global__ void hist_kernel(const int* __restrict__ ei, int* __restrict__ cnt) {
    int e = blockIdx.x * 256 + threadIdx.x;
    if (e < N_EDGES) atomicAdd(&cnt[ei[N_EDGES + e]], 1);
}

__global__ __launch_bounds__(1024) void scan_block_kernel(const int* __restrict__ cnt,
                                                          int* __restrict__ rs,
                                                          int* __restrict__ bsum, int n) {
    __shared__ int t[1024];
    int tid = threadIdx.x;
    int gid = blockIdx.x * 1024 + tid;
    int v = (gid < n) ? cnt[gid] : 0;
    t[tid] = v;
    __syncthreads();
    for (int off = 1; off < 1024; off <<= 1) {
        int u = (tid >= off) ? t[tid - off] : 0;
        __syncthreads();
        t[tid] += u;
        __syncthreads();
    }
    if (gid < n) rs[gid] = t[tid] - v;          // exclusive within block
    if (tid == 1023) bsum[blockIdx.x] = t[1023];
}

// finalize + cross-block sum scan (wave computes prefix of bsum inline)
__global__ void finalize2_kernel(const int* __restrict__ cnt, int* __restrict__ rs,
                                 int* __restrict__ cursor, float* __restrict__ dinv,
                                 const int* __restrict__ bsum) {
    __shared__ int chunk_off;
    int tid = threadIdx.x;
    int i = blockIdx.x * 256 + tid;
    int chunk = blockIdx.x >> 2;        // (blockIdx.x*256)>>10, uniform per block
    if (tid < 64) {
        int v = (tid < chunk) ? bsum[tid] : 0;
#pragma unroll
        for (int o = 1; o < 64; o <<= 1) v += __shfl_xor(v, o);
        if (tid == 0) chunk_off = v;
    }
    __syncthreads();
    if (i < N_NODES) {
        int v = rs[i] + chunk_off;
        rs[i] = v;
        cursor[i] = v;
        dinv[i] = 1.0f / fmaxf((float)cnt[i], 1.0f);
        if (i == 0) rs[N_NODES] = N_EDGES;
    }
}

__global__ void scatter_kernel(const int* __restrict__ ei, int* __restrict__ cursor,
                               int* __restrict__ csr) {
    int e = blockIdx.x * 256 + threadIdx.x;
    if (e < N_EDGES) {
        int d = ei[N_EDGES + e];
        int p = atomicAdd(&cursor[d], 1);
        csr[p] = ei[e];
    }
}

// ---------------------------------------------------------------------------
// Weight split, all 3 layers: w123h/l[layer][n][256] = split [Wl | Wr]
// ---------------------------------------------------------------------------
__global__ void split_w3_kernel(const float* __restrict__ Wl1, const float* __restrict__ Wr1,
                                const float* __restrict__ Wl2, const float* __restrict__ Wr2,
                                const float* __restrict__ Wl3, const float* __restrict__ Wr3,
                                unsigned short* __restrict__ hi, unsigned short* __restrict__ lo) {
    int layer = blockIdx.x >> 7;                       // 0..2
    int idx = (blockIdx.x & 127) * 256 + threadIdx.x;  // 0..32767
    int n = idx >> 8, k = idx & 255;
    const float* Wl = (layer == 0) ? Wl1 : (layer == 1) ? Wl2 : Wl3;
    const float* Wr = (layer == 0) ? Wr1 : (layer == 1) ? Wr2 : Wr3;
    float v = (k < 128) ? Wl[n * 128 + k] : Wr[n * 128 + (k - 128)];
    unsigned short h = f2bf(v);
    size_t o = (size_t)layer * 32768 + idx;
    hi[o] = h;
    lo[o] = f2bf(v - bf2f(h));
}

// Classifier weight split: wc_h/l[48][128] (rows 40..47 zero-padded)
__global__ void split_wc_kernel(const float* __restrict__ Wc,
                                unsigned short* __restrict__ hi, unsigned short* __restrict__ lo) {
    int idx = blockIdx.x * 256 + threadIdx.x;   // 0..6143
    int n = idx >> 7, k = idx & 127;
    float v = (n < N_CLS) ? Wc[n * 128 + k] : 0.f;
    unsigned short h = f2bf(v);
    hi[idx] = h;
    lo[idx] = f2bf(v - bf2f(h));
}

// ---------------------------------------------------------------------------
// Mean aggregation fp32 (layers 1-2, R6-proven): one wave per node.
// ---------------------------------------------------------------------------
__global__ __launch_bounds__(256) void agg_kernel(const float* __restrict__ feat,
                                                  const int* __restrict__ rs,
                                                  const int* __restrict__ csr,
                                                  const float* __restrict__ dinv,
                                                  float* __restrict__ aggn) {
    int wave = threadIdx.x >> 6;
    int lane = threadIdx.x & 63;
    int node = blockIdx.x * 4 + wave;
    if (node >= N_NODES) return;
    int e0 = rs[node], e1 = rs[node + 1];
    int half = lane >> 5;
    int fl = lane & 31;
    float ax = 0.f, ay = 0.f, az = 0.f, aw = 0.f;

    for (int base = e0; base < e1; base += 64) {
        int cnt = min(64, e1 - base);
        int idxv = (lane < cnt) ? csr[base + lane] : 0;
        int cnt2 = cnt & ~1;
        int j = 0;
        for (; j + 8 <= cnt2; j += 8) {
            int s0 = __shfl(idxv, j + half);
            int s1 = __shfl(idxv, j + 2 + half);
            int s2 = __shfl(idxv, j + 4 + half);
            int s3 = __shfl(idxv, j + 6 + half);
            float4 v0 = *(const float4*)&feat[(size_t)s0 * D + fl * 4];
            float4 v1 = *(const float4*)&feat[(size_t)s1 * D + fl * 4];
            float4 v2 = *(const float4*)&feat[(size_t)s2 * D + fl * 4];
            float4 v3 = *(const float4*)&feat[(size_t)s3 * D + fl * 4];
            ax += v0.x + v1.x + v2.x + v3.x;
            ay += v0.y + v1.y + v2.y + v3.y;
            az += v0.z + v1.z + v2.z + v3.z;
            aw += v0.w + v1.w + v2.w + v3.w;
        }
        for (; j < cnt2; j += 2) {
            int s = __shfl(idxv, j + half);
            float4 v = *(const float4*)&feat[(size_t)s * D + fl * 4];
            ax += v.x; ay += v.y; az += v.z; aw += v.w;
        }
        if (j < cnt) {
            int s = __shfl(idxv, j);
            if (half == 0) {
                float4 v = *(const float4*)&feat[(size_t)s * D + fl * 4];
                ax += v.x; ay += v.y; az += v.z; aw += v.w;
            }
        }
    }
    ax += __shfl(ax, lane ^ 32);
    ay += __shfl(ay, lane ^ 32);
    az += __shfl(az, lane ^ 32);
    aw += __shfl(aw, lane ^ 32);
    if (half == 0) {
        float di = dinv[node];
        float4 o; o.x = ax * di; o.y = ay * di; o.z = az * di; o.w = aw * di;
        *(float4*)&aggn[(size_t)node * D + fl * 4] = o;
    }
}

// ---------------------------------------------------------------------------
// Mean aggregation over int16 table (layer 3 only; R4-proven mechanics).
// Row = 256B; 16 lanes x 16B cover a row => one instr gathers FOUR rows.
// int32 accumulate (exact), dequant*deg_inv at the end.
// ---------------------------------------------------------------------------
__global__ __launch_bounds__(256) void agg_q_kernel(const short* __restrict__ feat16,
                                                    const int* __restrict__ rs,
                                                    const int* __restrict__ csr,
                                                    const float* __restrict__ dinv,
                                                    float* __restrict__ aggn) {
    int wave = threadIdx.x >> 6;
    int lane = threadIdx.x & 63;
    int node = blockIdx.x * 4 + wave;
    if (node >= N_NODES) return;
    int e0 = rs[node], e1 = rs[node + 1];
    int q = lane >> 4;          // edge sub-slot 0..3
    int fl = lane & 15;         // feature octet
    int acc[8] = {0, 0, 0, 0, 0, 0, 0, 0};

    auto acc8 = [&](uint4 u) {
        acc[0] += (int)(short)(u.x & 0xffff);
        acc[1] += (int)(short)(u.x >> 16);
        acc[2] += (int)(short)(u.y & 0xffff);
        acc[3] += (int)(short)(u.y >> 16);
        acc[4] += (int)(short)(u.z & 0xffff);
        acc[5] += (int)(short)(u.z >> 16);
        acc[6] += (int)(short)(u.w & 0xffff);
        acc[7] += (int)(short)(u.w >> 16);
    };

    for (int base = e0; base < e1; base += 64) {
        int cnt = min(64, e1 - base);
        int idxv = (lane < cnt) ? csr[base + lane] : 0;
        int bulk = cnt & ~15;
        int j = 0;
        for (; j < bulk; j += 16) {
            int s0 = __shfl(idxv, j + q);
            int s1 = __shfl(idxv, j + 4 + q);
            int s2 = __shfl(idxv, j + 8 + q);
            int s3 = __shfl(idxv, j + 12 + q);
            uint4 a = *(const uint4*)&feat16[(size_t)s0 * D + fl * 8];
            uint4 b = *(const uint4*)&feat16[(size_t)s1 * D + fl * 8];
            uint4 c = *(const uint4*)&feat16[(size_t)s2 * D + fl * 8];
            uint4 d = *(const uint4*)&feat16[(size_t)s3 * D + fl * 8];
            acc8(a); acc8(b); acc8(c); acc8(d);
        }
        for (; j < cnt; j += 4) {
            if (j + q < cnt) {
                int s = __shfl(idxv, j + q);
                uint4 a = *(const uint4*)&feat16[(size_t)s * D + fl * 8];
                acc8(a);
            }
        }
    }
#pragma unroll
    for (int i = 0; i < 8; ++i) {
        acc[i] += __shfl(acc[i], lane ^ 16);
        acc[i] += __shfl(acc[i], lane ^ 32);
    }
    if (q == 0) {
        float sc = dinv[node] * DQ;
        float4 o0, o1;
        o0.x = acc[0] * sc; o0.y = acc[1] * sc; o0.z = acc[2] * sc; o0.w = acc[3] * sc;
        o1.x = acc[4] * sc; o1.y = acc[5] * sc; o1.z = acc[6] * sc; o1.w = acc[7] * sc;
        *(float4*)&aggn[(size_t)node * D + fl * 8] = o0;
        *(float4*)&aggn[(size_t)node * D + fl * 8 + 4] = o1;
    }
}

// ---------------------------------------------------------------------------
// Split-bf16 MFMA GEMM, BK=32 (24KB LDS -> ~5 blocks/CU):
//   out = relu([Aagg|Ax] @ Wcat^T + bias); optional int16 twin store.
// Swizzle for 64B row stride: boff ^= (row&7)<<4 -> 16 lanes hit 8 bank-quads
// (2-way aliasing = free, G4/m136).
// ---------------------------------------------------------------------------
__global__ __launch_bounds__(256) void gemm_mfma_kernel(const float* __restrict__ Aagg,
                                                        const float* __restrict__ Ax,
                                                        const unsigned short* __restrict__ Whi,
                                                        const unsigned short* __restrict__ Wlo,
                                                        const float* __restrict__ bias,
                                                        short* __restrict__ out16,
                                                        float* __restrict__ outp, int M) {
    __shared__ __align__(16) unsigned short AhS[64 * 32];   // 4KB
    __shared__ __align__(16) unsigned short AlS[64 * 32];   // 4KB
    __shared__ __align__(16) unsigned short WhS[128 * 32];  // 8KB
    __shared__ __align__(16) unsigned short WlS[128 * 32];  // 8KB
    char* AhB = (char*)AhS;
    char* AlB = (char*)AlS;
    char* WhB = (char*)WhS;
    char* WlB = (char*)WlS;

    int tid = threadIdx.x;
    int lane = tid & 63;
    int wid = tid >> 6;
    int wr = wid >> 1;          // row half (32 rows)
    int wc = wid & 1;           // col half (64 cols)
    int lr = lane & 15;
    int kg = (lane >> 4) * 8;   // k-offset within 32-k step
    int row0 = blockIdx.x * 64;

    f32x4 acc[2][4];
#pragma unroll
    for (int f = 0; f < 2; ++f)
#pragma unroll
        for (int j = 0; j < 4; ++j) acc[f][j] = (f32x4){0.f, 0.f, 0.f, 0.f};

    for (int kt = 0; kt < 8; ++kt) {
        const float* Asrc = (kt < 4) ? Aagg : Ax;
        int kcol = (kt & 3) * 32;

        // stage A: 64 rows x 32 k = 256 slots of 8 floats (1 slot/thread)
        {
            int row = tid >> 2;
            int k8 = (tid & 3) * 8;
            int gr = row0 + row;
            if (gr >= M) gr = M - 1;
            const float* p = &Asrc[(size_t)gr * D + kcol + k8];
            float4 v0 = *(const float4*)p;
            float4 v1 = *(const float4*)(p + 4);
            float fv[8] = {v0.x, v0.y, v0.z, v0.w, v1.x, v1.y, v1.z, v1.w};
            union { unsigned short u[8]; uint4 q; } ph, pl;
#pragma unroll
            for (int j = 0; j < 8; ++j) {
                unsigned short h = f2bf(fv[j]);
                ph.u[j] = h;
                pl.u[j] = f2bf(fv[j] - bf2f(h));
            }
            int boff = (row << 6) + (k8 << 1);
            boff ^= (row & 7) << 4;
            *(uint4*)(AhB + boff) = ph.q;
            *(uint4*)(AlB + boff) = pl.q;
        }
        // stage W: 128 n x 32 k = 512 slots of 8 (2 slots/thread)
#pragma unroll
        for (int it = 0; it < 2; ++it) {
            int slot = tid + it * 256;
            int n = slot >> 2;
            int k8 = (slot & 3) * 8;
            size_t gsrc = (size_t)n * 256 + kt * 32 + k8;
            uint4 h = *(const uint4*)&Whi[gsrc];
            uint4 l = *(const uint4*)&Wlo[gsrc];
            int boff = (n << 6) + (k8 << 1);
            boff ^= (n & 7) << 4;
            *(uint4*)(WhB + boff) = h;
            *(uint4*)(WlB + boff) = l;
        }
        __syncthreads();

        // one 32-k MFMA step
        {
            bf16x8 ah[2], al[2];
#pragma unroll
            for (int f = 0; f < 2; ++f) {
                int row = wr * 32 + f * 16 + lr;
                int boff = (row << 6) + (kg << 1);
                boff ^= (row & 7) << 4;
                ah[f] = *(const bf16x8*)(AhB + boff);
                al[f] = *(const bf16x8*)(AlB + boff);
            }
            bf16x8 bh[4], bl[4];
#pragma unroll
            for (int j = 0; j < 4; ++j) {
                int n = wc * 64 + j * 16 + lr;
                int boff = (n << 6) + (kg << 1);
                boff ^= (n & 7) << 4;
                bh[j] = *(const bf16x8*)(WhB + boff);
                bl[j] = *(const bf16x8*)(WlB + boff);
            }
#pragma unroll
            for (int f = 0; f < 2; ++f)
#pragma unroll
                for (int j = 0; j < 4; ++j) {
                    acc[f][j] = __builtin_amdgcn_mfma_f32_16x16x32_bf16(ah[f], bh[j], acc[f][j], 0, 0, 0);
                    acc[f][j] = __builtin_amdgcn_mfma_f32_16x16x32_bf16(ah[f], bl[j], acc[f][j], 0, 0, 0);
                    acc[f][j] = __builtin_amdgcn_mfma_f32_16x16x32_bf16(al[f], bh[j], acc[f][j], 0, 0, 0);
                }
        }
        __syncthreads();
    }

    // epilogue: bias + relu (+ optional int16 twin). D map: row=(l>>4)*4+r, col=l&15
#pragma unroll
    for (int f = 0; f < 2; ++f)
#pragma unroll
        for (int j = 0; j < 4; ++j) {
            int c = wc * 64 + j * 16 + lr;
            float b = bias[c];
#pragma unroll
            for (int r = 0; r < 4; ++r) {
                int gr = row0 + wr * 32 + f * 16 + (lane >> 4) * 4 + r;
                if (gr < M) {
                    float v = fmaxf(acc[f][j][r] + b, 0.f);
                    outp[(size_t)gr * D + c] = v;
                    if (out16) out16[(size_t)gr * D + c] = q16(v);
                }
            }
        }
}

// ---------------------------------------------------------------------------
// Layer-3 GEMM + residual + fused classifier (unchanged from R6, 48KB LDS).
// ---------------------------------------------------------------------------
__global__ __launch_bounds__(256) void gemm_cls_kernel(const float* __restrict__ Aagg,
                                                       const float* __restrict__ Ax,
                                                       const unsigned short* __restrict__ Whi,
                                                       const unsigned short* __restrict__ Wlo,
                                                       const float* __restrict__ bias,
                                                       const float* __restrict__ residf,
                                                       const unsigned short* __restrict__ Wch,
                                                       const unsigned short* __restrict__ Wcl,
                                                       const float* __restrict__ bc,
                                                       float* __restrict__ outp, int M) {
    __shared__ __align__(16) char smem[49152];
    char* AhB = smem;
    char* AlB = smem + 8192;
    char* WhB = smem + 16384;
    char* WlB = smem + 32768;

    int tid = threadIdx.x;
    int lane = tid & 63;
    int wid = tid >> 6;
    int wr = wid >> 1;
    int wc = wid & 1;
    int lr = lane & 15;
    int kg = (lane >> 4) * 8;
    int row0 = blockIdx.x * 64;

    f32x4 acc[2][4];
#pragma unroll
    for (int f = 0; f < 2; ++f)
#pragma unroll
        for (int j = 0; j < 4; ++j) acc[f][j] = (f32x4){0.f, 0.f, 0.f, 0.f};

    for (int kt = 0; kt < 4; ++kt) {
        const float* Asrc = (kt < 2) ? Aagg : Ax;
        int kcol = (kt & 1) * 64;
#pragma unroll
        for (int it = 0; it < 2; ++it) {
            int slot = tid + it * 256;
            int row = slot >> 3;
            int k8 = (slot & 7) * 8;
            int gr = row0 + row;
            if (gr >= M) gr = M - 1;
            const float* p = &Asrc[(size_t)gr * D + kcol + k8];
            float4 v0 = *(const float4*)p;
            float4 v1 = *(const float4*)(p + 4);
            float fv[8] = {v0.x, v0.y, v0.z, v0.w, v1.x, v1.y, v1.z, v1.w};
            union { unsigned short u[8]; uint4 q; } ph, pl;
#pragma unroll
            for (int j = 0; j < 8; ++j) {
                unsigned short h = f2bf(fv[j]);
                ph.u[j] = h;
                pl.u[j] = f2bf(fv[j] - bf2f(h));
            }
            int boff = (row << 7) + (k8 << 1);
            boff ^= (row & 7) << 4;
            *(uint4*)(AhB + boff) = ph.q;
            *(uint4*)(AlB + boff) = pl.q;
        }
#pragma unroll
        for (int it = 0; it < 4; ++it) {
            int slot = tid + it * 256;
            int n = slot >> 3;
            int k8 = (slot & 7) * 8;
            size_t gsrc = (size_t)n * 256 + kt * 64 + k8;
            uint4 h = *(const uint4*)&Whi[gsrc];
            uint4 l = *(const uint4*)&Wlo[gsrc];
            int boff = (n << 7) + (k8 << 1);
            boff ^= (n & 7) << 4;
            *(uint4*)(WhB + boff) = h;
            *(uint4*)(WlB + boff) = l;
        }
        __syncthreads();
#pragma unroll
        for (int ks = 0; ks < 2; ++ks) {
            int kk = ks * 32 + kg;
            bf16x8 ah[2], al[2];
#pragma unroll
            for (int f = 0; f < 2; ++f) {
                int row = wr * 32 + f * 16 + lr;
                int boff = (row << 7) + (kk << 1);
                boff ^= (row & 7) << 4;
                ah[f] = *(const bf16x8*)(AhB + boff);
                al[f] = *(const bf16x8*)(AlB + boff);
            }
            bf16x8 bh[4], bl[4];
#pragma unroll
            for (int j = 0; j < 4; ++j) {
                int n = wc * 64 + j * 16 + lr;
                int boff = (n << 7) + (kk << 1);
                boff ^= (n & 7) << 4;
                bh[j] = *(const bf16x8*)(WhB + boff);
                bl[j] = *(const bf16x8*)(WlB + boff);
            }
#pragma unroll
            for (int f = 0; f < 2; ++f)
#pragma unroll
                for (int j = 0; j < 4; ++j) {
                    acc[f][j] = __builtin_amdgcn_mfma_f32_16x16x32_bf16(ah[f], bh[j], acc[f][j], 0, 0, 0);
                    acc[f][j] = __builtin_amdgcn_mfma_f32_16x16x32_bf16(ah[f], bl[j], acc[f][j], 0, 0, 0);
                    acc[f][j] = __builtin_amdgcn_mfma_f32_16x16x32_bf16(al[f], bh[j], acc[f][j], 0, 0, 0);
                }
        }
        __syncthreads();
    }

    // classifier: 2 phases over vif col-halves (vif kept in LDS)
    f32x4 acc2[3];
#pragma unroll
    for (int j = 0; j < 3; ++j) acc2[j] = (f32x4){0.f, 0.f, 0.f, 0.f};

    for (int p = 0; p < 2; ++p) {
#pragma unroll
        for (int it = 0; it < 2; ++it) {
            int slot = tid + it * 256;
            if (slot < 384) {
                int n = slot >> 3;
                int k8 = (slot & 7) * 8;
                size_t gsrc = (size_t)n * 128 + p * 64 + k8;
                uint4 h = *(const uint4*)&Wch[gsrc];
                uint4 l = *(const uint4*)&Wcl[gsrc];
                int boff = (n << 7) + (k8 << 1);
                boff ^= (n & 7) << 4;
                *(uint4*)(WhB + boff) = h;
                *(uint4*)(WlB + boff) = l;
            }
        }
        if (wc == p) {
#pragma unroll
            for (int f = 0; f < 2; ++f)
#pragma unroll
                for (int j = 0; j < 4; ++j) {
                    int c = wc * 64 + j * 16 + lr;
                    float b = bias[c];
#pragma unroll
                    for (int r = 0; r < 4; ++r) {
                        int row = wr * 32 + f * 16 + (lane >> 4) * 4 + r;
                        int gr = row0 + row;
                        int gra = (gr < M) ? gr : (M - 1);
                        float v = fmaxf(acc[f][j][r] + b, 0.f);
                        v += residf[(size_t)gra * D + c];
                        int kloc = j * 16 + lr;
                        int boff = (row << 7) + (kloc << 1);
                        boff ^= (row & 7) << 4;
                        unsigned short h = f2bf(v);
                        *(unsigned short*)(AhB + boff) = h;
                        *(unsigned short*)(AlB + boff) = f2bf(v - bf2f(h));
                    }
                }
        }
        __syncthreads();

#pragma unroll
        for (int ks = 0; ks < 2; ++ks) {
            int kk = ks * 32 + kg;
            int row = wid * 16 + lr;
            int boffA = (row << 7) + (kk << 1);
            boffA ^= (row & 7) << 4;
            bf16x8 ah = *(const bf16x8*)(AhB + boffA);
            bf16x8 al = *(const bf16x8*)(AlB + boffA);
#pragma unroll
            for (int j = 0; j < 3; ++j) {
                int n = j * 16 + lr;
                int boffB = (n << 7) + (kk << 1);
                boffB ^= (n & 7) << 4;
                bf16x8 bh = *(const bf16x8*)(WhB + boffB);
                bf16x8 bl = *(const bf16x8*)(WlB + boffB);
                acc2[j] = __builtin_amdgcn_mfma_f32_16x16x32_bf16(ah, bh, acc2[j], 0, 0, 0);
                acc2[j] = __builtin_amdgcn_mfma_f32_16x16x32_bf16(ah, bl, acc2[j], 0, 0, 0);
                acc2[j] = __builtin_amdgcn_mfma_f32_16x16x32_bf16(al, bh, acc2[j], 0, 0, 0);
            }
        }
        __syncthreads();
    }

#pragma unroll
    for (int j = 0; j < 3; ++j) {
        int c = j * 16 + lr;
        if (c < N_CLS) {
            float b = bc[c];
#pragma unroll
            for (int r = 0; r < 4; ++r) {
                int gr = row0 + wid * 16 + (lane >> 4) * 4 + r;
                if (gr < M) outp[(size_t)gr * N_CLS + c] = acc2[j][r] + b;
            }
        }
    }
}

// ---------------------------------------------------------------------------
extern "C" void kernel_launch(void* const* d_in, const int* in_sizes, int n_in,
                              void* d_out, int out_size, void* d_ws, size_t ws_size,
                              hipStream_t stream) {
    const float* x   = (const float*)d_in[0];
    const int*   ei  = (const int*)d_in[1];
    const float* Wl1 = (const float*)d_in[2];
    const float* bl1 = (const float*)d_in[3];
    const float* Wr1 = (const float*)d_in[4];
    const float* Wl2 = (const float*)d_in[5];
    const float* bl2 = (const float*)d_in[6];
    const float* Wr2 = (const float*)d_in[7];
    const float* Wl3 = (const float*)d_in[8];
    const float* bl3 = (const float*)d_in[9];
    const float* Wr3 = (const float*)d_in[10];
    const float* Wc  = (const float*)d_in[11];
    const float* bc  = (const float*)d_in[12];
    float* out = (float*)d_out;

    char* w = (char*)d_ws;
    size_t off = 0;
    auto carve = [&](size_t bytes) -> void* {
        void* p = w + off;
        off = (off + bytes + 255) & ~(size_t)255;
        return p;
    };
    int*   cnt    = (int*)carve((size_t)N_NODES * 4);
    int*   rs     = (int*)carve((size_t)(N_NODES + 1) * 4);
    int*   cursor = (int*)carve((size_t)N_NODES * 4);
    float* dinv   = (float*)carve((size_t)N_NODES * 4);
    int*   bsum   = (int*)carve(64 * 4);
    int*   csr    = (int*)carve((size_t)N_EDGES * 4);
    float* aggn   = (float*)carve((size_t)N_NODES * D * 4);   // 25.6 MB
    float* bufA   = (float*)carve((size_t)N_NODES * D * 4);   // 25.6 MB
    float* bufB   = (float*)carve((size_t)N_NODES * D * 4);   // 25.6 MB
    short* t16    = (short*)carve((size_t)N_NODES * D * 2);   // 12.8 MB L3 gather twin
    unsigned short* w123h = (unsigned short*)carve(3 * 128 * 256 * 2);
    unsigned short* w123l = (unsigned short*)carve(3 * 128 * 256 * 2);
    unsigned short* wch   = (unsigned short*)carve(48 * 128 * 2);
    unsigned short* wcl   = (unsigned short*)carve(48 * 128 * 2);
    (void)ws_size;

    const int NBLK_SCAN = (N_NODES + 1023) / 1024;           // 49
    const int GRID_E = (N_EDGES + 255) / 256;                // 2344
    const int GRID_N = (N_NODES + 255) / 256;                // 196
    const int GRID_AGG = (N_NODES + 3) / 4;                  // 12500
    const int GRID_GEMM = (N_NODES + 63) / 64;               // 782

    // CSR build + weight splits
    hipMemsetAsync(cnt, 0, (size_t)N_NODES * 4, stream);
    hipLaunchKernelGGL(hist_kernel, dim3(GRID_E), dim3(256), 0, stream, ei, cnt);
    hipLaunchKernelGGL(split_w3_kernel, dim3(384), dim3(256), 0, stream,
                       Wl1, Wr1, Wl2, Wr2, Wl3, Wr3, w123h, w123l);
    hipLaunchKernelGGL(split_wc_kernel, dim3(24), dim3(256), 0, stream, Wc, wch, wcl);
    hipLaunchKernelGGL(scan_block_kernel, dim3(NBLK_SCAN), dim3(1024), 0, stream, cnt, rs, bsum, N_NODES);
    hipLaunchKernelGGL(finalize2_kernel, dim3(GRID_N), dim3(256), 0, stream, cnt, rs, cursor, dinv, bsum);
    hipLaunchKernelGGL(scatter_kernel, dim3(GRID_E), dim3(256), 0, stream, ei, cursor, csr);

    // Layer 1: agg fp32 -> GEMM -> bufA
    hipLaunchKernelGGL(agg_kernel, dim3(GRID_AGG), dim3(256), 0, stream, x, rs, csr, dinv, aggn);
    hipLaunchKernelGGL(gemm_mfma_kernel, dim3(GRID_GEMM), dim3(256), 0, stream,
                       aggn, x, w123h, w123l, bl1, (short*)nullptr, bufA, N_NODES);
    // Layer 2: agg fp32 -> GEMM -> bufB + t16 twin (for L3 gather)
    hipLaunchKernelGGL(agg_kernel, dim3(GRID_AGG), dim3(256), 0, stream, bufA, rs, csr, dinv, aggn);
    hipLaunchKernelGGL(gemm_mfma_kernel, dim3(GRID_GEMM), dim3(256), 0, stream,
                       aggn, bufA, w123h + 32768, w123l + 32768, bl2, t16, bufB, N_NODES);
    // Layer 3: agg int16 -> GEMM + resid + classifier
    hipLaunchKernelGGL(agg_q_kernel, dim3(GRID_AGG), dim3(256), 0, stream, t16, rs, csr, dinv, aggn);
    hipLaunchKernelGGL(gemm_cls_kernel, dim3(GRID_GEMM), dim3(256), 0, stream,
                       aggn, bufB, w123h + 65536, w123l + 65536, bl3, bufB,
                       wch, wcl, bc, out, N_NODES);
}